// Round 3
// baseline (586.784 us; speedup 1.0000x reference)
//
#include <hip/hip_runtime.h>
#include <hip/hip_bf16.h>

#define BSZ 4
#define NN  256
#define DXX 256
#define DEE 64
#define DYY 64

// ---- workspace layout (float offsets) ----
#define OFF_Q     0          // 262144
#define OFF_K     262144     // 262144
#define OFF_V     524288     // 262144
#define OFF_XW    786432     // 262144
#define OFF_YE1   1048576    // 1024
#define OFF_YE2   1049600    // 1024
#define OFF_YX1   1050624    // 1024
#define OFF_YX2   1051648    // 1024
#define OFF_PX    1052672    // 4096
#define OFF_EPART 1057792    // 65536
// total ~1123328 floats = 4.5 MB

typedef __attribute__((ext_vector_type(8))) short bf16x8;
typedef __attribute__((ext_vector_type(4))) float f32x4;

__device__ __forceinline__ short f2bf(float f) {
    unsigned u = __float_as_uint(f);
    unsigned r = u + 0x7fffu + ((u >> 16) & 1u);
    return (short)(r >> 16);
}

// ================= PREP: qkv (192 blocks) + yproj (4) + epoolA (256) + xpool (4) =================
__global__ __launch_bounds__(256) void prep_kernel(
    const float* __restrict__ x, const float* __restrict__ e, const float* __restrict__ y,
    const float* __restrict__ nm,
    const float* __restrict__ Wq, const float* __restrict__ Wk, const float* __restrict__ Wv,
    const float* __restrict__ Wye_add, const float* __restrict__ Wye_mul,
    const float* __restrict__ Wyx_add, const float* __restrict__ Wyx_mul,
    float* __restrict__ ws) {

    __shared__ float smem[16 * 256];
    const int blk = blockIdx.x;
    const int t = threadIdx.x;

    if (blk < 192) {
        // ---- qkv ----
        const int m0 = (blk & 63) * 16;
        const int which = blk >> 6;
        const float* W = which == 0 ? Wq : (which == 1 ? Wk : Wv);
        float* out = ws + (size_t)which * 262144;
        float (*xl)[256] = (float(*)[256])smem;
        for (int r = 0; r < 16; ++r) xl[r][t] = x[(m0 + r) * 256 + t];
        __syncthreads();
        float acc[16];
#pragma unroll
        for (int r = 0; r < 16; ++r) acc[r] = 0.f;
        for (int d = 0; d < 256; d += 4) {
            float w0 = W[(d + 0) * 256 + t];
            float w1 = W[(d + 1) * 256 + t];
            float w2 = W[(d + 2) * 256 + t];
            float w3 = W[(d + 3) * 256 + t];
#pragma unroll
            for (int r = 0; r < 16; ++r) {
                float4 ev = *(const float4*)&xl[r][d];
                acc[r] = fmaf(ev.x, w0, fmaf(ev.y, w1, fmaf(ev.z, w2, fmaf(ev.w, w3, acc[r]))));
            }
        }
#pragma unroll
        for (int r = 0; r < 16; ++r) {
            int m = m0 + r;
            out[m * 256 + t] = acc[r] * nm[m];
        }
    } else if (blk < 196) {
        // ---- yproj ----
        const int b = blk - 192;
        float a1 = 0.f, a2 = 0.f, a3 = 0.f, a4 = 0.f;
        for (int k = 0; k < DYY; ++k) {
            float yv = y[b * DYY + k];
            a1 = fmaf(yv, Wye_add[k * 256 + t], a1);
            a2 = fmaf(yv, Wye_mul[k * 256 + t], a2);
            a3 = fmaf(yv, Wyx_add[k * 256 + t], a3);
            a4 = fmaf(yv, Wyx_mul[k * 256 + t], a4);
        }
        ws[OFF_YE1 + b * 256 + t] = a1;
        ws[OFF_YE2 + b * 256 + t] = a2;
        ws[OFF_YX1 + b * 256 + t] = a3;
        ws[OFF_YX2 + b * 256 + t] = a4;
    } else if (blk < 452) {
        // ---- epoolA partials ----
        const int idx = blk - 196;
        const int s = idx & 63, b = idx >> 6;
        const int d = t & 63, g = t >> 6;
        const float* base = e + ((size_t)b * 65536 + s * 1024) * 64;
        float sum = 0.f, sq = 0.f, mn = 1e30f, mx = -1e30f;
        for (int rr = 0; rr < 256; ++rr) {
            float v = base[(rr * 4 + g) * 64 + d];
            sum += v; sq = fmaf(v, v, sq);
            mn = fminf(mn, v); mx = fmaxf(mx, v);
        }
        float (*red)[4][64] = (float(*)[4][64])smem;
        red[0][g][d] = sum; red[1][g][d] = sq; red[2][g][d] = mn; red[3][g][d] = mx;
        __syncthreads();
        if (g == 0) {
            float S = 0.f, Q = 0.f, Mn = 1e30f, Mx = -1e30f;
#pragma unroll
            for (int gg = 0; gg < 4; ++gg) {
                S += red[0][gg][d]; Q += red[1][gg][d];
                Mn = fminf(Mn, red[2][gg][d]); Mx = fmaxf(Mx, red[3][gg][d]);
            }
            float* ep = ws + OFF_EPART + ((b * 64 + s) * 64 + d) * 4;
            ep[0] = S; ep[1] = Q; ep[2] = Mn; ep[3] = Mx;
        }
    } else {
        // ---- xpool ----
        const int b = blk - 452;
        float s = 0.f, q = 0.f, mn = 1e30f, mx = -1e30f;
        for (int i = 0; i < 256; ++i) {
            float v = x[(b * 256 + i) * 256 + t];
            s += v; q = fmaf(v, v, q);
            mn = fminf(mn, v); mx = fmaxf(mx, v);
        }
        float mean = s * (1.f / 256.f);
        float var  = (q - s * s * (1.f / 256.f)) * (1.f / 255.f);
        var = fmaxf(var, 0.f);
        ws[OFF_PX + b * 1024 + t]       = mean;
        ws[OFF_PX + b * 1024 + 256 + t] = mn;
        ws[OFF_PX + b * 1024 + 512 + t] = mx;
        ws[OFF_PX + b * 1024 + 768 + t] = sqrtf(var);
    }
}

// ================= FUSED: E1/E2 (MFMA) + Y + online softmax + newE (MFMA) + xw =================
#define EBP  72
#define YPLP 264

__global__ __launch_bounds__(256, 3) void fusedmfma_kernel(
    const float* __restrict__ e, const float* __restrict__ nmask,
    const float* __restrict__ Wm, const float* __restrict__ Wa,
    const float* __restrict__ We_out, const float* __restrict__ be_out,
    const float* __restrict__ ws, float* __restrict__ outE, float* __restrict__ xw) {

    const int i = blockIdx.x, b = blockIdx.y;
    const int tid  = threadIdx.x;
    const int w    = tid >> 6;
    const int lane = tid & 63;
    const int quad = lane >> 4, l16 = lane & 15;

    __shared__ __align__(16) short ebuf[2][32 * EBP];
    __shared__ __align__(16) short ypl[32 * YPLP];
    __shared__ float nml[256];

    nml[tid] = nmask[b * 256 + tid];

    bf16x8 bm[4][2], ba[4][2], bw[8];
    const int cw = w * 64;
#pragma unroll
    for (int ct = 0; ct < 4; ++ct) {
        const int c = cw + ct * 16 + l16;
#pragma unroll
        for (int s = 0; s < 2; ++s) {
            bf16x8 t1, t2;
#pragma unroll
            for (int jj = 0; jj < 8; ++jj) {
                const int d = s * 32 + quad * 8 + jj;
                t1[jj] = f2bf(Wm[d * 256 + c]);
                t2[jj] = f2bf(Wa[d * 256 + c]);
            }
            bm[ct][s] = t1; ba[ct][s] = t2;
        }
    }
    const int cp = w * 16 + l16;
    {
#pragma unroll
        for (int s = 0; s < 8; ++s) {
            bf16x8 t;
#pragma unroll
            for (int jj = 0; jj < 8; ++jj) {
                const int cch = s * 32 + quad * 8 + jj;
                t[jj] = f2bf(We_out[cch * 64 + cp]);
            }
            bw[s] = t;
        }
    }
    const float bo = be_out[cp];

    const float rs = 0.17677669529663687f;
    float qc[4], ye1c[4], ye2c[4];
#pragma unroll
    for (int ct = 0; ct < 4; ++ct) {
        const int c = cw + ct * 16 + l16;
        qc[ct]   = ws[OFF_Q + (size_t)(b * 256 + i) * 256 + c] * rs;
        ye1c[ct] = ws[OFF_YE1 + b * 256 + c];
        ye2c[ct] = ws[OFF_YE2 + b * 256 + c] + 1.f;
    }
    const float* kb = ws + OFF_K + (size_t)b * 65536;
    const float* vb = ws + OFF_V + (size_t)b * 65536;

    const float* eb = e + ((size_t)(b * 256 + i)) * 256 * 64;
    {
        const int jr = tid >> 3, c0 = (tid & 7) * 8;
        float4 A = *(const float4*)(eb + jr * 64 + c0);
        float4 B = *(const float4*)(eb + jr * 64 + c0 + 4);
        short* dst = &ebuf[0][jr * EBP + c0];
        dst[0] = f2bf(A.x); dst[1] = f2bf(A.y); dst[2] = f2bf(A.z); dst[3] = f2bf(A.w);
        dst[4] = f2bf(B.x); dst[5] = f2bf(B.y); dst[6] = f2bf(B.z); dst[7] = f2bf(B.w);
    }
    __syncthreads();
    const float mi = nml[i];

    float msm[4], lsm[4], wsm[4];
#pragma unroll
    for (int ct = 0; ct < 4; ++ct) { msm[ct] = -1e30f; lsm[ct] = 0.f; wsm[ct] = 0.f; }

    for (int chunk = 0; chunk < 8; ++chunk) {
        const int cur = chunk & 1, j0 = chunk * 32;

        bf16x8 ae[2][2];
#pragma unroll
        for (int jt = 0; jt < 2; ++jt)
#pragma unroll
            for (int s = 0; s < 2; ++s)
                ae[jt][s] = *(const bf16x8*)&ebuf[cur][(jt * 16 + l16) * EBP + s * 32 + quad * 8];

        float4 pfA, pfB;
        const int jrn = tid >> 3, c0n = (tid & 7) * 8;
        if (chunk < 7) {
            const float* nb = eb + (size_t)(j0 + 32 + jrn) * 64 + c0n;
            pfA = *(const float4*)(nb);
            pfB = *(const float4*)(nb + 4);
        }

        // em = mi*mj for this lane's 8 rows; select uses em>0 (equivalent to mj>0
        // whenever mi>0; when mi==0 downstream x_mask/em zeroing makes it irrelevant)
        float emv[8];
#pragma unroll
        for (int jt = 0; jt < 2; ++jt)
#pragma unroll
            for (int r = 0; r < 4; ++r)
                emv[jt * 4 + r] = mi * nml[j0 + jt * 16 + quad * 4 + r];

#pragma unroll
        for (int ct = 0; ct < 4; ++ct) {
            f32x4 a1_0 = {0.f, 0.f, 0.f, 0.f}, a1_1 = {0.f, 0.f, 0.f, 0.f};
            f32x4 a2_0 = {0.f, 0.f, 0.f, 0.f}, a2_1 = {0.f, 0.f, 0.f, 0.f};
#pragma unroll
            for (int s = 0; s < 2; ++s) {
                a1_0 = __builtin_amdgcn_mfma_f32_16x16x32_bf16(ae[0][s], bm[ct][s], a1_0, 0, 0, 0);
                a1_1 = __builtin_amdgcn_mfma_f32_16x16x32_bf16(ae[1][s], bm[ct][s], a1_1, 0, 0, 0);
                a2_0 = __builtin_amdgcn_mfma_f32_16x16x32_bf16(ae[0][s], ba[ct][s], a2_0, 0, 0, 0);
                a2_1 = __builtin_amdgcn_mfma_f32_16x16x32_bf16(ae[1][s], ba[ct][s], a2_1, 0, 0, 0);
            }
            const int c = cw + ct * 16 + l16;
            float Ys[8], Vs[8];
#pragma unroll
            for (int jt = 0; jt < 2; ++jt) {
#pragma unroll
                for (int r = 0; r < 4; ++r) {
                    const int u  = jt * 4 + r;
                    const int jl = jt * 16 + quad * 4 + r;
                    const int jg = j0 + jl;
                    const float kj = kb[jg * 256 + c];
                    const float vj = vb[jg * 256 + c];
                    const float e1v = (jt == 0) ? a1_0[r] : a1_1[r];
                    const float e2v = (jt == 0) ? a2_0[r] : a2_1[r];
                    const float em = emv[u];
                    const float Yv = fmaf(qc[ct] * kj, fmaf(e1v, em, 1.f), e2v * em);
                    ypl[jl * YPLP + c] = f2bf(fmaf(ye2c[ct], Yv, ye1c[ct]));
                    Ys[u] = (em > 0.f) ? Yv : -1e9f;
                    Vs[u] = vj;
                }
            }
            float cm = Ys[0];
#pragma unroll
            for (int u = 1; u < 8; ++u) cm = fmaxf(cm, Ys[u]);
            const float mnew = fmaxf(msm[ct], cm);
            const float al = __expf(msm[ct] - mnew);
            float sum = 0.f, wsum = 0.f;
#pragma unroll
            for (int u = 0; u < 8; ++u) {
                const float p = __expf(Ys[u] - mnew);
                sum += p; wsum = fmaf(p, Vs[u], wsum);
            }
            lsm[ct] = fmaf(lsm[ct], al, sum);
            wsm[ct] = fmaf(wsm[ct], al, wsum);
            msm[ct] = mnew;
        }

        if (chunk < 7) {
            short* dst = &ebuf[cur ^ 1][jrn * EBP + c0n];
            dst[0] = f2bf(pfA.x); dst[1] = f2bf(pfA.y); dst[2] = f2bf(pfA.z); dst[3] = f2bf(pfA.w);
            dst[4] = f2bf(pfB.x); dst[5] = f2bf(pfB.y); dst[6] = f2bf(pfB.z); dst[7] = f2bf(pfB.w);
        }
        __syncthreads();

        f32x4 acc0 = {0.f, 0.f, 0.f, 0.f}, acc1 = {0.f, 0.f, 0.f, 0.f};
#pragma unroll
        for (int s = 0; s < 8; ++s) {
            bf16x8 a0 = *(const bf16x8*)&ypl[(l16) * YPLP + s * 32 + quad * 8];
            bf16x8 a1 = *(const bf16x8*)&ypl[(16 + l16) * YPLP + s * 32 + quad * 8];
            acc0 = __builtin_amdgcn_mfma_f32_16x16x32_bf16(a0, bw[s], acc0, 0, 0, 0);
            acc1 = __builtin_amdgcn_mfma_f32_16x16x32_bf16(a1, bw[s], acc1, 0, 0, 0);
        }
#pragma unroll
        for (int jt = 0; jt < 2; ++jt)
#pragma unroll
            for (int r = 0; r < 4; ++r) {
                const int jg = j0 + jt * 16 + quad * 4 + r;
                const float em2 = mi * nml[jg];
                const float av = (jt == 0) ? acc0[r] : acc1[r];
                outE[((size_t)(b * 256 + i) * 256 + jg) * 64 + cp] = (av + bo) * em2;
            }
        __syncthreads();
    }

#pragma unroll
    for (int ct = 0; ct < 4; ++ct) {
        float m = msm[ct], l = lsm[ct], wv = wsm[ct];
#pragma unroll
        for (int off = 16; off < 64; off <<= 1) {
            const float m2 = __shfl_xor(m, off, 64);
            const float l2 = __shfl_xor(l, off, 64);
            const float w2 = __shfl_xor(wv, off, 64);
            const float mn = fmaxf(m, m2);
            const float s1 = __expf(m - mn), s2 = __expf(m2 - mn);
            l = l * s1 + l2 * s2;
            wv = wv * s1 + w2 * s2;
            m = mn;
        }
        if (quad == 0) {
            const int c = cw + ct * 16 + l16;
            const float weighted = wv / l;
            const float yx1 = ws[OFF_YX1 + b * 256 + c];
            const float yx2 = ws[OFF_YX2 + b * 256 + c] + 1.f;
            xw[(size_t)(b * 256 + i) * 256 + c] = fmaf(yx2, weighted, yx1);
        }
    }
}

// ================= POST: rowgemm (64 blocks) + e-pool combine + newY (1 block) =================
__global__ __launch_bounds__(256) void post_kernel(
    const float* __restrict__ xwin, const float* __restrict__ Wx_out,
    const float* __restrict__ bx_out, const float* __restrict__ nm,
    const float* __restrict__ y,
    const float* __restrict__ Wyy, const float* __restrict__ Wxy,
    const float* __restrict__ bxy, const float* __restrict__ Wey,
    const float* __restrict__ bey, const float* __restrict__ Wy_out,
    const float* __restrict__ by_out,
    const float* __restrict__ ws, float* __restrict__ outX, float* __restrict__ outY) {

    __shared__ float smem[16 * 256];
    const int blk = blockIdx.x;
    const int t = threadIdx.x;

    if (blk < 64) {
        // ---- newX = xw @ Wx_out + bx_out, masked ----
        const int m0 = blk * 16;
        float (*xl)[256] = (float(*)[256])smem;
        for (int r = 0; r < 16; ++r) xl[r][t] = xwin[(m0 + r) * 256 + t];
        __syncthreads();
        float acc[16];
#pragma unroll
        for (int r = 0; r < 16; ++r) acc[r] = 0.f;
        for (int d = 0; d < 256; d += 4) {
            float w0 = Wx_out[(d + 0) * 256 + t];
            float w1 = Wx_out[(d + 1) * 256 + t];
            float w2 = Wx_out[(d + 2) * 256 + t];
            float w3 = Wx_out[(d + 3) * 256 + t];
#pragma unroll
            for (int r = 0; r < 16; ++r) {
                float4 ev = *(const float4*)&xl[r][d];
                acc[r] = fmaf(ev.x, w0, fmaf(ev.y, w1, fmaf(ev.z, w2, fmaf(ev.w, w3, acc[r]))));
            }
        }
        const float bv = bx_out[t];
#pragma unroll
        for (int r = 0; r < 16; ++r) {
            int m = m0 + r;
            outX[m * 256 + t] = (acc[r] + bv) * nm[m];
        }
    } else {
        // ---- e-pool combine + newY ----
        float* pe = smem;          // 1024 floats: [b][cat][64]
        float* sy = smem + 1024;   // 256 floats
        {
            const int b = t >> 6, d = t & 63;
            float S = 0.f, Q = 0.f, Mn = 1e30f, Mx = -1e30f;
            for (int ss = 0; ss < 64; ++ss) {
                const float* ep = ws + OFF_EPART + ((b * 64 + ss) * 64 + d) * 4;
                float4 p = *(const float4*)ep;
                S += p.x; Q += p.y; Mn = fminf(Mn, p.z); Mx = fmaxf(Mx, p.w);
            }
            const float n = 65536.f;
            float meane = S / n;
            float vare  = (Q - S * S / n) / (n - 1.f);
            vare = fmaxf(vare, 0.f);
            pe[b * 256 + d]       = meane;
            pe[b * 256 + 64 + d]  = Mn;
            pe[b * 256 + 128 + d] = Mx;
            pe[b * 256 + 192 + d] = sqrtf(vare);
        }
        __syncthreads();
        const int b = t >> 6, o = t & 63;
        float a = bxy[o] + bey[o];
        for (int k = 0; k < 64; ++k)   a = fmaf(y[b * 64 + k],          Wyy[k * 64 + o], a);
        for (int k = 0; k < 256; ++k)  a = fmaf(pe[b * 256 + k],        Wey[k * 64 + o], a);
        for (int k = 0; k < 1024; ++k) a = fmaf(ws[OFF_PX + b * 1024 + k], Wxy[k * 64 + o], a);
        sy[b * 64 + o] = a;
        __syncthreads();
        float r = by_out[o];
        for (int k = 0; k < 64; ++k) r = fmaf(sy[b * 64 + k], Wy_out[k * 64 + o], r);
        outY[b * 64 + o] = r;
    }
}

extern "C" void kernel_launch(void* const* d_in, const int* in_sizes, int n_in,
                              void* d_out, int out_size, void* d_ws, size_t ws_size,
                              hipStream_t stream) {
    const float* x        = (const float*)d_in[0];
    const float* e        = (const float*)d_in[1];
    const float* y        = (const float*)d_in[2];
    const float* nm       = (const float*)d_in[3];
    const float* Wq       = (const float*)d_in[4];
    const float* Wk       = (const float*)d_in[5];
    const float* Wv       = (const float*)d_in[6];
    const float* We_mul   = (const float*)d_in[7];
    const float* We_add   = (const float*)d_in[8];
    const float* Wye_add  = (const float*)d_in[9];
    const float* Wye_mul  = (const float*)d_in[10];
    const float* Wyx_add  = (const float*)d_in[11];
    const float* Wyx_mul  = (const float*)d_in[12];
    const float* Wyy      = (const float*)d_in[13];
    const float* Wxy      = (const float*)d_in[14];
    const float* bxy      = (const float*)d_in[15];
    const float* Wey      = (const float*)d_in[16];
    const float* bey      = (const float*)d_in[17];
    const float* We_out   = (const float*)d_in[18];
    const float* be_out   = (const float*)d_in[19];
    const float* Wx_out   = (const float*)d_in[20];
    const float* bx_out   = (const float*)d_in[21];
    const float* Wy_out   = (const float*)d_in[22];
    const float* by_out   = (const float*)d_in[23];

    float* ws   = (float*)d_ws;
    float* outX = (float*)d_out;
    float* outE = (float*)d_out + 262144;
    float* outY = (float*)d_out + 262144 + 16777216;

    prep_kernel<<<456, 256, 0, stream>>>(x, e, y, nm, Wq, Wk, Wv,
                                         Wye_add, Wye_mul, Wyx_add, Wyx_mul, ws);
    fusedmfma_kernel<<<dim3(256, 4), 256, 0, stream>>>(e, nm, We_mul, We_add, We_out, be_out,
                                                       ws, outE, ws + OFF_XW);
    post_kernel<<<65, 256, 0, stream>>>(ws + OFF_XW, Wx_out, bx_out, nm, y,
                                        Wyy, Wxy, bxy, Wey, bey, Wy_out, by_out,
                                        ws, outX, outY);
}

// Round 4
// 370.919 us; speedup vs baseline: 1.5820x; 1.5820x over previous
//
#include <hip/hip_runtime.h>
#include <hip/hip_bf16.h>

#define BSZ 4
#define NN  256
#define DXX 256
#define DEE 64
#define DYY 64

// ---- workspace layout (float offsets) ----
#define OFF_Q     0          // 262144
#define OFF_K     262144     // 262144
#define OFF_V     524288     // 262144
#define OFF_XW    786432     // 262144
#define OFF_YE1   1048576    // 1024
#define OFF_YE2   1049600    // 1024
#define OFF_YX1   1050624    // 1024
#define OFF_YX2   1051648    // 1024
#define OFF_PX    1052672    // 4096
#define OFF_EPART 1057792    // 65536
// total ~1123328 floats = 4.5 MB

typedef __attribute__((ext_vector_type(8))) short bf16x8;
typedef __attribute__((ext_vector_type(4))) float f32x4;

__device__ __forceinline__ short f2bf(float f) {
    unsigned u = __float_as_uint(f);
    unsigned r = u + 0x7fffu + ((u >> 16) & 1u);
    return (short)(r >> 16);
}

// ================= PREP: qkv (192 blocks) + yproj (4) + epoolA (256) + xpool (4) =================
__global__ __launch_bounds__(256) void prep_kernel(
    const float* __restrict__ x, const float* __restrict__ e, const float* __restrict__ y,
    const float* __restrict__ nm,
    const float* __restrict__ Wq, const float* __restrict__ Wk, const float* __restrict__ Wv,
    const float* __restrict__ Wye_add, const float* __restrict__ Wye_mul,
    const float* __restrict__ Wyx_add, const float* __restrict__ Wyx_mul,
    float* __restrict__ ws) {

    __shared__ float smem[16 * 256];
    const int blk = blockIdx.x;
    const int t = threadIdx.x;

    if (blk < 192) {
        const int m0 = (blk & 63) * 16;
        const int which = blk >> 6;
        const float* W = which == 0 ? Wq : (which == 1 ? Wk : Wv);
        float* out = ws + (size_t)which * 262144;
        float (*xl)[256] = (float(*)[256])smem;
        for (int r = 0; r < 16; ++r) xl[r][t] = x[(m0 + r) * 256 + t];
        __syncthreads();
        float acc[16];
#pragma unroll
        for (int r = 0; r < 16; ++r) acc[r] = 0.f;
        for (int d = 0; d < 256; d += 4) {
            float w0 = W[(d + 0) * 256 + t];
            float w1 = W[(d + 1) * 256 + t];
            float w2 = W[(d + 2) * 256 + t];
            float w3 = W[(d + 3) * 256 + t];
#pragma unroll
            for (int r = 0; r < 16; ++r) {
                float4 ev = *(const float4*)&xl[r][d];
                acc[r] = fmaf(ev.x, w0, fmaf(ev.y, w1, fmaf(ev.z, w2, fmaf(ev.w, w3, acc[r]))));
            }
        }
#pragma unroll
        for (int r = 0; r < 16; ++r) {
            int m = m0 + r;
            out[m * 256 + t] = acc[r] * nm[m];
        }
    } else if (blk < 196) {
        const int b = blk - 192;
        float a1 = 0.f, a2 = 0.f, a3 = 0.f, a4 = 0.f;
        for (int k = 0; k < DYY; ++k) {
            float yv = y[b * DYY + k];
            a1 = fmaf(yv, Wye_add[k * 256 + t], a1);
            a2 = fmaf(yv, Wye_mul[k * 256 + t], a2);
            a3 = fmaf(yv, Wyx_add[k * 256 + t], a3);
            a4 = fmaf(yv, Wyx_mul[k * 256 + t], a4);
        }
        ws[OFF_YE1 + b * 256 + t] = a1;
        ws[OFF_YE2 + b * 256 + t] = a2;
        ws[OFF_YX1 + b * 256 + t] = a3;
        ws[OFF_YX2 + b * 256 + t] = a4;
    } else if (blk < 452) {
        const int idx = blk - 196;
        const int s = idx & 63, b = idx >> 6;
        const int d = t & 63, g = t >> 6;
        const float* base = e + ((size_t)b * 65536 + s * 1024) * 64;
        float sum = 0.f, sq = 0.f, mn = 1e30f, mx = -1e30f;
        for (int rr = 0; rr < 256; ++rr) {
            float v = base[(rr * 4 + g) * 64 + d];
            sum += v; sq = fmaf(v, v, sq);
            mn = fminf(mn, v); mx = fmaxf(mx, v);
        }
        float (*red)[4][64] = (float(*)[4][64])smem;
        red[0][g][d] = sum; red[1][g][d] = sq; red[2][g][d] = mn; red[3][g][d] = mx;
        __syncthreads();
        if (g == 0) {
            float S = 0.f, Q = 0.f, Mn = 1e30f, Mx = -1e30f;
#pragma unroll
            for (int gg = 0; gg < 4; ++gg) {
                S += red[0][gg][d]; Q += red[1][gg][d];
                Mn = fminf(Mn, red[2][gg][d]); Mx = fmaxf(Mx, red[3][gg][d]);
            }
            float* ep = ws + OFF_EPART + ((b * 64 + s) * 64 + d) * 4;
            ep[0] = S; ep[1] = Q; ep[2] = Mn; ep[3] = Mx;
        }
    } else {
        const int b = blk - 452;
        float s = 0.f, q = 0.f, mn = 1e30f, mx = -1e30f;
        for (int i = 0; i < 256; ++i) {
            float v = x[(b * 256 + i) * 256 + t];
            s += v; q = fmaf(v, v, q);
            mn = fminf(mn, v); mx = fmaxf(mx, v);
        }
        float mean = s * (1.f / 256.f);
        float var  = (q - s * s * (1.f / 256.f)) * (1.f / 255.f);
        var = fmaxf(var, 0.f);
        ws[OFF_PX + b * 1024 + t]       = mean;
        ws[OFF_PX + b * 1024 + 256 + t] = mn;
        ws[OFF_PX + b * 1024 + 512 + t] = mx;
        ws[OFF_PX + b * 1024 + 768 + t] = sqrtf(var);
    }
}

// ================= FUSED: E1/E2 (MFMA) + Y + online softmax + newE (MFMA) + xw =================
// NOTE: weight frags (bm/ba/bw = 96 VGPR) are register-resident; forcing 3 waves/SIMD
// via __launch_bounds__ spills them to scratch (R2: FETCH 54->470 MB). Keep (256,2).
#define EBP  72
#define YPLP 264

__global__ __launch_bounds__(256, 2) void fusedmfma_kernel(
    const float* __restrict__ e, const float* __restrict__ nmask,
    const float* __restrict__ Wm, const float* __restrict__ Wa,
    const float* __restrict__ We_out, const float* __restrict__ be_out,
    const float* __restrict__ ws, float* __restrict__ outE, float* __restrict__ xw) {

    const int i = blockIdx.x, b = blockIdx.y;
    const int tid  = threadIdx.x;
    const int w    = tid >> 6;
    const int lane = tid & 63;
    const int quad = lane >> 4, l16 = lane & 15;

    __shared__ __align__(16) short ebuf[2][32 * EBP];
    __shared__ __align__(16) short ypl[32 * YPLP];
    __shared__ float nml[256];

    nml[tid] = nmask[b * 256 + tid];

    bf16x8 bm[4][2], ba[4][2], bw[8];
    const int cw = w * 64;
#pragma unroll
    for (int ct = 0; ct < 4; ++ct) {
        const int c = cw + ct * 16 + l16;
#pragma unroll
        for (int s = 0; s < 2; ++s) {
            bf16x8 t1, t2;
#pragma unroll
            for (int jj = 0; jj < 8; ++jj) {
                const int d = s * 32 + quad * 8 + jj;
                t1[jj] = f2bf(Wm[d * 256 + c]);
                t2[jj] = f2bf(Wa[d * 256 + c]);
            }
            bm[ct][s] = t1; ba[ct][s] = t2;
        }
    }
    const int cp = w * 16 + l16;
    {
#pragma unroll
        for (int s = 0; s < 8; ++s) {
            bf16x8 t;
#pragma unroll
            for (int jj = 0; jj < 8; ++jj) {
                const int cch = s * 32 + quad * 8 + jj;
                t[jj] = f2bf(We_out[cch * 64 + cp]);
            }
            bw[s] = t;
        }
    }
    const float bo = be_out[cp];

    const float rs = 0.17677669529663687f;
    float qc[4], ye1c[4], ye2c[4];
#pragma unroll
    for (int ct = 0; ct < 4; ++ct) {
        const int c = cw + ct * 16 + l16;
        qc[ct]   = ws[OFF_Q + (size_t)(b * 256 + i) * 256 + c] * rs;
        ye1c[ct] = ws[OFF_YE1 + b * 256 + c];
        ye2c[ct] = ws[OFF_YE2 + b * 256 + c] + 1.f;
    }
    const float* kb = ws + OFF_K + (size_t)b * 65536;
    const float* vb = ws + OFF_V + (size_t)b * 65536;

    const float* eb = e + ((size_t)(b * 256 + i)) * 256 * 64;
    {
        const int jr = tid >> 3, c0 = (tid & 7) * 8;
        float4 A = *(const float4*)(eb + jr * 64 + c0);
        float4 B = *(const float4*)(eb + jr * 64 + c0 + 4);
        short* dst = &ebuf[0][jr * EBP + c0];
        dst[0] = f2bf(A.x); dst[1] = f2bf(A.y); dst[2] = f2bf(A.z); dst[3] = f2bf(A.w);
        dst[4] = f2bf(B.x); dst[5] = f2bf(B.y); dst[6] = f2bf(B.z); dst[7] = f2bf(B.w);
    }
    __syncthreads();
    const float mi = nml[i];

    float msm[4], lsm[4], wsm[4];
#pragma unroll
    for (int ct = 0; ct < 4; ++ct) { msm[ct] = -1e30f; lsm[ct] = 0.f; wsm[ct] = 0.f; }

    for (int chunk = 0; chunk < 8; ++chunk) {
        const int cur = chunk & 1, j0 = chunk * 32;

        bf16x8 ae[2][2];
#pragma unroll
        for (int jt = 0; jt < 2; ++jt)
#pragma unroll
            for (int s = 0; s < 2; ++s)
                ae[jt][s] = *(const bf16x8*)&ebuf[cur][(jt * 16 + l16) * EBP + s * 32 + quad * 8];

        float4 pfA, pfB;
        const int jrn = tid >> 3, c0n = (tid & 7) * 8;
        if (chunk < 7) {
            const float* nb = eb + (size_t)(j0 + 32 + jrn) * 64 + c0n;
            pfA = *(const float4*)(nb);
            pfB = *(const float4*)(nb + 4);
        }

        float emv[8];
#pragma unroll
        for (int jt = 0; jt < 2; ++jt)
#pragma unroll
            for (int r = 0; r < 4; ++r)
                emv[jt * 4 + r] = mi * nml[j0 + jt * 16 + quad * 4 + r];

        for (int ct = 0; ct < 4; ++ct) {
            const int c = cw + ct * 16 + l16;
            // issue k/v loads FIRST so their L2 latency overlaps the MFMA chain below
            float Ks[8], Vs[8];
#pragma unroll
            for (int jt = 0; jt < 2; ++jt)
#pragma unroll
                for (int r = 0; r < 4; ++r) {
                    const int jg = j0 + jt * 16 + quad * 4 + r;
                    Ks[jt * 4 + r] = kb[jg * 256 + c];
                    Vs[jt * 4 + r] = vb[jg * 256 + c];
                }

            f32x4 a1_0 = {0.f, 0.f, 0.f, 0.f}, a1_1 = {0.f, 0.f, 0.f, 0.f};
            f32x4 a2_0 = {0.f, 0.f, 0.f, 0.f}, a2_1 = {0.f, 0.f, 0.f, 0.f};
#pragma unroll
            for (int s = 0; s < 2; ++s) {
                a1_0 = __builtin_amdgcn_mfma_f32_16x16x32_bf16(ae[0][s], bm[ct][s], a1_0, 0, 0, 0);
                a1_1 = __builtin_amdgcn_mfma_f32_16x16x32_bf16(ae[1][s], bm[ct][s], a1_1, 0, 0, 0);
                a2_0 = __builtin_amdgcn_mfma_f32_16x16x32_bf16(ae[0][s], ba[ct][s], a2_0, 0, 0, 0);
                a2_1 = __builtin_amdgcn_mfma_f32_16x16x32_bf16(ae[1][s], ba[ct][s], a2_1, 0, 0, 0);
            }

            float Ys[8];
#pragma unroll
            for (int jt = 0; jt < 2; ++jt) {
#pragma unroll
                for (int r = 0; r < 4; ++r) {
                    const int u  = jt * 4 + r;
                    const int jl = jt * 16 + quad * 4 + r;
                    const float e1v = (jt == 0) ? a1_0[r] : a1_1[r];
                    const float e2v = (jt == 0) ? a2_0[r] : a2_1[r];
                    const float em = emv[u];
                    const float Yv = fmaf(qc[ct] * Ks[u], fmaf(e1v, em, 1.f), e2v * em);
                    ypl[jl * YPLP + c] = f2bf(fmaf(ye2c[ct], Yv, ye1c[ct]));
                    Ys[u] = (em > 0.f) ? Yv : -1e9f;
                }
            }
            float cm = Ys[0];
#pragma unroll
            for (int u = 1; u < 8; ++u) cm = fmaxf(cm, Ys[u]);
            const float mnew = fmaxf(msm[ct], cm);
            const float al = __expf(msm[ct] - mnew);
            float sum = 0.f, wsum = 0.f;
#pragma unroll
            for (int u = 0; u < 8; ++u) {
                const float p = __expf(Ys[u] - mnew);
                sum += p; wsum = fmaf(p, Vs[u], wsum);
            }
            lsm[ct] = fmaf(lsm[ct], al, sum);
            wsm[ct] = fmaf(wsm[ct], al, wsum);
            msm[ct] = mnew;
        }

        if (chunk < 7) {
            short* dst = &ebuf[cur ^ 1][jrn * EBP + c0n];
            dst[0] = f2bf(pfA.x); dst[1] = f2bf(pfA.y); dst[2] = f2bf(pfA.z); dst[3] = f2bf(pfA.w);
            dst[4] = f2bf(pfB.x); dst[5] = f2bf(pfB.y); dst[6] = f2bf(pfB.z); dst[7] = f2bf(pfB.w);
        }
        __syncthreads();

        f32x4 acc0 = {0.f, 0.f, 0.f, 0.f}, acc1 = {0.f, 0.f, 0.f, 0.f};
#pragma unroll
        for (int s = 0; s < 8; ++s) {
            bf16x8 a0 = *(const bf16x8*)&ypl[(l16) * YPLP + s * 32 + quad * 8];
            bf16x8 a1 = *(const bf16x8*)&ypl[(16 + l16) * YPLP + s * 32 + quad * 8];
            acc0 = __builtin_amdgcn_mfma_f32_16x16x32_bf16(a0, bw[s], acc0, 0, 0, 0);
            acc1 = __builtin_amdgcn_mfma_f32_16x16x32_bf16(a1, bw[s], acc1, 0, 0, 0);
        }
#pragma unroll
        for (int jt = 0; jt < 2; ++jt)
#pragma unroll
            for (int r = 0; r < 4; ++r) {
                const int jg = j0 + jt * 16 + quad * 4 + r;
                const float em2 = mi * nml[jg];
                const float av = (jt == 0) ? acc0[r] : acc1[r];
                outE[((size_t)(b * 256 + i) * 256 + jg) * 64 + cp] = (av + bo) * em2;
            }
        __syncthreads();
    }

#pragma unroll
    for (int ct = 0; ct < 4; ++ct) {
        float m = msm[ct], l = lsm[ct], wv = wsm[ct];
#pragma unroll
        for (int off = 16; off < 64; off <<= 1) {
            const float m2 = __shfl_xor(m, off, 64);
            const float l2 = __shfl_xor(l, off, 64);
            const float w2 = __shfl_xor(wv, off, 64);
            const float mn = fmaxf(m, m2);
            const float s1 = __expf(m - mn), s2 = __expf(m2 - mn);
            l = l * s1 + l2 * s2;
            wv = wv * s1 + w2 * s2;
            m = mn;
        }
        if (quad == 0) {
            const int c = cw + ct * 16 + l16;
            const float weighted = wv / l;
            const float yx1 = ws[OFF_YX1 + b * 256 + c];
            const float yx2 = ws[OFF_YX2 + b * 256 + c] + 1.f;
            xw[(size_t)(b * 256 + i) * 256 + c] = fmaf(yx2, weighted, yx1);
        }
    }
}

// ================= POST: rowgemm (64 blocks) + e-pool combine + newY (1 block) =================
__global__ __launch_bounds__(256) void post_kernel(
    const float* __restrict__ xwin, const float* __restrict__ Wx_out,
    const float* __restrict__ bx_out, const float* __restrict__ nm,
    const float* __restrict__ y,
    const float* __restrict__ Wyy, const float* __restrict__ Wxy,
    const float* __restrict__ bxy, const float* __restrict__ Wey,
    const float* __restrict__ bey, const float* __restrict__ Wy_out,
    const float* __restrict__ by_out,
    const float* __restrict__ ws, float* __restrict__ outX, float* __restrict__ outY) {

    __shared__ float smem[16 * 256];
    const int blk = blockIdx.x;
    const int t = threadIdx.x;

    if (blk < 64) {
        const int m0 = blk * 16;
        float (*xl)[256] = (float(*)[256])smem;
        for (int r = 0; r < 16; ++r) xl[r][t] = xwin[(m0 + r) * 256 + t];
        __syncthreads();
        float acc[16];
#pragma unroll
        for (int r = 0; r < 16; ++r) acc[r] = 0.f;
        for (int d = 0; d < 256; d += 4) {
            float w0 = Wx_out[(d + 0) * 256 + t];
            float w1 = Wx_out[(d + 1) * 256 + t];
            float w2 = Wx_out[(d + 2) * 256 + t];
            float w3 = Wx_out[(d + 3) * 256 + t];
#pragma unroll
            for (int r = 0; r < 16; ++r) {
                float4 ev = *(const float4*)&xl[r][d];
                acc[r] = fmaf(ev.x, w0, fmaf(ev.y, w1, fmaf(ev.z, w2, fmaf(ev.w, w3, acc[r]))));
            }
        }
        const float bv = bx_out[t];
#pragma unroll
        for (int r = 0; r < 16; ++r) {
            int m = m0 + r;
            outX[m * 256 + t] = (acc[r] + bv) * nm[m];
        }
    } else {
        float* pe = smem;
        float* sy = smem + 1024;
        {
            const int b = t >> 6, d = t & 63;
            float S = 0.f, Q = 0.f, Mn = 1e30f, Mx = -1e30f;
            for (int ss = 0; ss < 64; ++ss) {
                const float* ep = ws + OFF_EPART + ((b * 64 + ss) * 64 + d) * 4;
                float4 p = *(const float4*)ep;
                S += p.x; Q += p.y; Mn = fminf(Mn, p.z); Mx = fmaxf(Mx, p.w);
            }
            const float n = 65536.f;
            float meane = S / n;
            float vare  = (Q - S * S / n) / (n - 1.f);
            vare = fmaxf(vare, 0.f);
            pe[b * 256 + d]       = meane;
            pe[b * 256 + 64 + d]  = Mn;
            pe[b * 256 + 128 + d] = Mx;
            pe[b * 256 + 192 + d] = sqrtf(vare);
        }
        __syncthreads();
        const int b = t >> 6, o = t & 63;
        float a = bxy[o] + bey[o];
        for (int k = 0; k < 64; ++k)   a = fmaf(y[b * 64 + k],          Wyy[k * 64 + o], a);
        for (int k = 0; k < 256; ++k)  a = fmaf(pe[b * 256 + k],        Wey[k * 64 + o], a);
        for (int k = 0; k < 1024; ++k) a = fmaf(ws[OFF_PX + b * 1024 + k], Wxy[k * 64 + o], a);
        sy[b * 64 + o] = a;
        __syncthreads();
        float r = by_out[o];
        for (int k = 0; k < 64; ++k) r = fmaf(sy[b * 64 + k], Wy_out[k * 64 + o], r);
        outY[b * 64 + o] = r;
    }
}

extern "C" void kernel_launch(void* const* d_in, const int* in_sizes, int n_in,
                              void* d_out, int out_size, void* d_ws, size_t ws_size,
                              hipStream_t stream) {
    const float* x        = (const float*)d_in[0];
    const float* e        = (const float*)d_in[1];
    const float* y        = (const float*)d_in[2];
    const float* nm       = (const float*)d_in[3];
    const float* Wq       = (const float*)d_in[4];
    const float* Wk       = (const float*)d_in[5];
    const float* Wv       = (const float*)d_in[6];
    const float* We_mul   = (const float*)d_in[7];
    const float* We_add   = (const float*)d_in[8];
    const float* Wye_add  = (const float*)d_in[9];
    const float* Wye_mul  = (const float*)d_in[10];
    const float* Wyx_add  = (const float*)d_in[11];
    const float* Wyx_mul  = (const float*)d_in[12];
    const float* Wyy      = (const float*)d_in[13];
    const float* Wxy      = (const float*)d_in[14];
    const float* bxy      = (const float*)d_in[15];
    const float* Wey      = (const float*)d_in[16];
    const float* bey      = (const float*)d_in[17];
    const float* We_out   = (const float*)d_in[18];
    const float* be_out   = (const float*)d_in[19];
    const float* Wx_out   = (const float*)d_in[20];
    const float* bx_out   = (const float*)d_in[21];
    const float* Wy_out   = (const float*)d_in[22];
    const float* by_out   = (const float*)d_in[23];

    float* ws   = (float*)d_ws;
    float* outX = (float*)d_out;
    float* outE = (float*)d_out + 262144;
    float* outY = (float*)d_out + 262144 + 16777216;

    prep_kernel<<<456, 256, 0, stream>>>(x, e, y, nm, Wq, Wk, Wv,
                                         Wye_add, Wye_mul, Wyx_add, Wyx_mul, ws);
    fusedmfma_kernel<<<dim3(256, 4), 256, 0, stream>>>(e, nm, We_mul, We_add, We_out, be_out,
                                                       ws, outE, ws + OFF_XW);
    post_kernel<<<65, 256, 0, stream>>>(ws + OFF_XW, Wx_out, bx_out, nm, y,
                                        Wyy, Wxy, bxy, Wey, bey, Wy_out, by_out,
                                        ws, outX, outY);
}